// Round 8
// baseline (156.004 us; speedup 1.0000x reference)
//
#include <hip/hip_runtime.h>
#include <math.h>

#define C_ 8
#define B_ 4
#define T_ 4096
#define D_ 128
#define TT 64
#define NCH (T_ / TT)                       // 64 chunks
#define CBTD ((size_t)C_ * B_ * T_ * D_)    // 16777216
#define SSIZE ((size_t)2 * C_ * B_ * NCH * D_)  // 524288 floats

typedef __attribute__((ext_vector_type(8))) short short8;
typedef __attribute__((ext_vector_type(4))) float f32x4;

__device__ __forceinline__ float lam_of(int c) {
  return (float)(1.0 - exp2(-(double)c * (13.0 / 7.0)));
}

__device__ __forceinline__ float decay_pow(float lam, float l2lam, int n) {
  if (n == 0) return 1.0f;
  if (lam == 0.0f) return 0.0f;
  return exp2f((float)n * l2lam);
}

__device__ __forceinline__ unsigned short f2bf(float x) {
  unsigned u = __float_as_uint(x);
  unsigned r = (u + 0x7FFFu + ((u >> 16) & 1u)) >> 16;   // RNE
  return (unsigned short)r;
}

// ---- pre-kernel: W (f32 [dir][c][d][e]) -> bf16 transposed Wt[dir*8+c][e][d]
__global__ __launch_bounds__(256)
void wcvt_kernel(const float* __restrict__ Wf, const float* __restrict__ Wb,
                 unsigned short* __restrict__ Wt) {
  __shared__ unsigned short Tq[128][130];
  const int blk = blockIdx.x;          // dir*8 + c
  const float* src = ((blk & 8) ? Wb : Wf) + (size_t)(blk & 7) * D_ * D_;
  const int tid = threadIdx.x;
  for (int i = 0; i < 16; ++i) {
    int fidx = tid + 256 * i;          // 4096 float4 chunks
    int d = fidx >> 5, e4 = (fidx & 31) * 4;
    float4 v = *(const float4*)(src + (size_t)d * D_ + e4);
    Tq[e4 + 0][d] = f2bf(v.x);
    Tq[e4 + 1][d] = f2bf(v.y);
    Tq[e4 + 2][d] = f2bf(v.z);
    Tq[e4 + 3][d] = f2bf(v.w);
  }
  __syncthreads();
  unsigned short* dst = Wt + (size_t)blk * D_ * D_;
  for (int i = 0; i < 8; ++i) {
    int fidx = tid + 256 * i;          // 2048 chunks of 8 bf16
    int e = fidx >> 4, d8 = (fidx & 15) * 8;
    unsigned short tmp[8];
    #pragma unroll
    for (int q = 0; q < 8; ++q) tmp[q] = Tq[e][d8 + q];
    #pragma unroll
    for (int q = 0; q < 8; ++q) dst[(size_t)e * D_ + d8 + q] = tmp[q];
  }
}

// ---- Phase A: one (dir,c,b,tile) per block; rolled f-loop; h kept in LDS
__global__ __launch_bounds__(256)
void gate_mfma_kernel(const float* __restrict__ z,
                      const unsigned short* __restrict__ Wt,
                      const float* __restrict__ bf, const float* __restrict__ bb,
                      float* __restrict__ out, float* __restrict__ S) {
  __shared__ float zh[64][132];    // z tile -> overwritten by local_h (33.8 KB)
  __shared__ float term[16][132];  // group terminals -> carries (8.4 KB)

  const int bi = blockIdx.x;       // ((dir*C + c)*B + b)*NCH + tile
  const int tile = bi & (NCH - 1);
  const int b = (bi >> 6) & 3;
  const int c = (bi >> 8) & 7;
  const int dir = bi >> 11;
  const int tid = threadIdx.x;
  const int lane = tid & 63;
  const int w = tid >> 6;
  const int l15 = lane & 15;
  const int l4 = lane >> 4;

  const float lam = lam_of(c);
  float lp[5];
  lp[0] = 1.f;
  #pragma unroll
  for (int i = 1; i < 5; ++i) lp[i] = lp[i - 1] * lam;

  const float* zsrc = z + ((size_t)(c * B_ + b) * T_ + tile * TT) * D_;

  // stage z tile coalesced
  #pragma unroll
  for (int i = 0; i < 8; ++i) {
    int fidx = tid + 256 * i;
    int row = fidx >> 5, col4 = (fidx & 31) * 4;
    *(float4*)&zh[row][col4] = *(const float4*)(zsrc + (size_t)row * D_ + col4);
  }
  __syncthreads();

  // A-fragments from LDS
  short8 afrag[4];
  const int rowA = w * 16 + l15;
  #pragma unroll
  for (int ks = 0; ks < 4; ++ks) {
    const float* p = &zh[rowA][ks * 32 + l4 * 8];
    f32x4 a0 = *(const f32x4*)p;
    f32x4 a1 = *(const f32x4*)(p + 4);
    short8 t;
    t[0] = (short)f2bf(a0.x); t[1] = (short)f2bf(a0.y);
    t[2] = (short)f2bf(a0.z); t[3] = (short)f2bf(a0.w);
    t[4] = (short)f2bf(a1.x); t[5] = (short)f2bf(a1.y);
    t[6] = (short)f2bf(a1.z); t[7] = (short)f2bf(a1.w);
    afrag[ks] = t;
  }

  const unsigned short* wt = Wt + (size_t)(dir * 8 + c) * D_ * D_;
  const float* bias = (dir ? bb : bf) + (size_t)c * D_;
  const int rowE = w * 16 + l4 * 4;

  // 1-deep pipelined rolled f-loop; wave touches only its own 16 rows -> no barrier
  short8 bcur[4];
  {
    const unsigned short* wb0 = wt + (size_t)(0 * 16 + l15) * D_ + l4 * 8;
    #pragma unroll
    for (int ks = 0; ks < 4; ++ks) bcur[ks] = *(const short8*)(wb0 + ks * 32);
  }
  #pragma unroll 1
  for (int f = 0; f < 8; ++f) {
    short8 bnxt[4];
    if (f < 7) {
      const unsigned short* wbn = wt + (size_t)((f + 1) * 16 + l15) * D_ + l4 * 8;
      #pragma unroll
      for (int ks = 0; ks < 4; ++ks) bnxt[ks] = *(const short8*)(wbn + ks * 32);
    }
    f32x4 acc = (f32x4){0.f, 0.f, 0.f, 0.f};
    #pragma unroll
    for (int ks = 0; ks < 4; ++ks)
      acc = __builtin_amdgcn_mfma_f32_16x16x32_bf16(afrag[ks], bcur[ks], acc, 0, 0, 0);

    const int col = f * 16 + l15;
    const float bcol = bias[col];
    float h = 0.f;
    if (dir == 0) {
      #pragma unroll
      for (int r = 0; r < 4; ++r) {
        const float g = 1.0f / (1.0f + __expf(-(acc[r] + bcol)));
        h = fmaf(lam, h, g * zh[rowE + r][col]);
        zh[rowE + r][col] = h;
      }
    } else {
      #pragma unroll
      for (int r = 3; r >= 0; --r) {
        const float g = 1.0f / (1.0f + __expf(-(acc[r] + bcol)));
        h = fmaf(lam, h, g * zh[rowE + r][col]);
        zh[rowE + r][col] = h;
      }
    }
    term[w * 4 + l4][col] = h;     // group terminal
    #pragma unroll
    for (int ks = 0; ks < 4; ++ks) bcur[ks] = bnxt[ks];
  }
  __syncthreads();

  // 16-group prefix per column; S = chunk terminal
  if (tid < 128) {
    float p = 0.f;
    const float l4p = lp[4];
    if (dir == 0) {
      #pragma unroll
      for (int g = 0; g < 16; ++g) { float t = term[g][tid]; term[g][tid] = p; p = fmaf(l4p, p, t); }
    } else {
      #pragma unroll
      for (int g = 15; g >= 0; --g) { float t = term[g][tid]; term[g][tid] = p; p = fmaf(l4p, p, t); }
    }
    S[(((size_t)(dir * C_ + c) * B_ + b) * NCH + tile) * D_ + tid] = p;
  }
  __syncthreads();

  // carry-fused coalesced nontemporal stores
  float* dst = out + (size_t)dir * CBTD +
               ((size_t)(c * B_ + b) * T_ + tile * TT) * D_;
  #pragma unroll
  for (int i = 0; i < 8; ++i) {
    int fidx = tid + 256 * i;
    int row = fidx >> 5, col4 = (fidx & 31) * 4;
    int r = row & 3;
    const float dec = (dir == 0) ? lp[r + 1] : lp[4 - r];
    f32x4 hv = *(const f32x4*)&zh[row][col4];
    f32x4 cv = *(const f32x4*)&term[row >> 2][col4];
    hv.x = fmaf(dec, cv.x, hv.x);
    hv.y = fmaf(dec, cv.y, hv.y);
    hv.z = fmaf(dec, cv.z, hv.z);
    hv.w = fmaf(dec, cv.w, hv.w);
    __builtin_nontemporal_store(hv, (f32x4*)(dst + (size_t)row * D_ + col4));
  }
}

// ---- Phase B: carry prefix across chunks (tiny)
__global__ __launch_bounds__(128)
void prefix_kernel(const float* __restrict__ S, float* __restrict__ Cin) {
  const int bi = blockIdx.x;        // (dir, c, b)
  const int dir = bi >> 5;
  const int c = (bi >> 2) & 7;
  const int b = bi & 3;
  const int e = threadIdx.x;
  const float lam = lam_of(c);
  const float l2lam = (lam > 0.f) ? log2f(lam) : 0.f;
  const float lamL = decay_pow(lam, l2lam, TT);
  const size_t base = ((size_t)(dir * C_ + c) * B_ + b) * NCH * D_ + e;
  float cin = 0.f;
  if (dir == 0) {
    for (int k = 0; k < NCH; ++k) {
      Cin[base + (size_t)k * D_] = cin;
      cin = fmaf(lamL, cin, S[base + (size_t)k * D_]);
    }
  } else {
    for (int k = NCH - 1; k >= 0; --k) {
      Cin[base + (size_t)k * D_] = cin;
      cin = fmaf(lamL, cin, S[base + (size_t)k * D_]);
    }
  }
}

// ---- Phase C: elementwise carry application, h += lam^dist * carry (c=0 skipped)
__global__ __launch_bounds__(256)
void apply_kernel(float* __restrict__ out, const float* __restrict__ Cin) {
  const int bi = blockIdx.x;          // ((dir*C + c)*B + b)*NCH + k
  const int k = bi & (NCH - 1);
  const int b = (bi >> 6) & 3;
  const int c = (bi >> 8) & 7;
  const int dir = bi >> 11;
  if (c == 0) return;                 // lam=0 -> carry always 0
  const float lam = lam_of(c);
  const float l2lam = log2f(lam);
  const int tid = threadIdx.x;
  const int col4 = (tid & 31) * 4;

  const f32x4 carry = *(const f32x4*)
      (Cin + (((size_t)(dir * C_ + c) * B_ + b) * NCH + k) * D_ + col4);
  float* base = out + (size_t)dir * CBTD +
                ((size_t)(c * B_ + b) * T_ + k * TT) * D_;
  #pragma unroll
  for (int i = 0; i < 8; ++i) {
    const int row = (tid >> 5) + i * 8;
    const int dist = (dir == 0) ? (row + 1) : (TT - row);
    const float dec = exp2f(l2lam * (float)dist);
    f32x4* p = (f32x4*)(base + (size_t)row * D_ + col4);
    f32x4 h = __builtin_nontemporal_load(p);
    h.x = fmaf(dec, carry.x, h.x);
    h.y = fmaf(dec, carry.y, h.y);
    h.z = fmaf(dec, carry.z, h.z);
    h.w = fmaf(dec, carry.w, h.w);
    __builtin_nontemporal_store(h, p);
  }
}

extern "C" void kernel_launch(void* const* d_in, const int* in_sizes, int n_in,
                              void* d_out, int out_size, void* d_ws, size_t ws_size,
                              hipStream_t stream) {
  const float* z  = (const float*)d_in[0];
  const float* Wf = (const float*)d_in[1];
  const float* bf = (const float*)d_in[2];
  const float* Wb = (const float*)d_in[3];
  const float* bb = (const float*)d_in[4];
  float* out = (float*)d_out;
  float* S   = (float*)d_ws;                      // 2 MB
  float* Cin = S + SSIZE;                         // 2 MB
  unsigned short* Wt = (unsigned short*)(Cin + SSIZE);  // 512 KB bf16

  wcvt_kernel<<<dim3(16), dim3(256), 0, stream>>>(Wf, Wb, Wt);
  gate_mfma_kernel<<<dim3(2 * C_ * B_ * NCH), dim3(256), 0, stream>>>(
      z, Wt, bf, bb, out, S);
  prefix_kernel<<<dim3(2 * C_ * B_), dim3(128), 0, stream>>>(S, Cin);
  apply_kernel<<<dim3(2 * C_ * B_ * NCH), dim3(256), 0, stream>>>(out, Cin);
}